// Round 3
// baseline (204.339 us; speedup 1.0000x reference)
//
#include <hip/hip_runtime.h>
#include <math.h>

#define BB 32
#define NN 8732
#define CC 21
#define TOPK 200
#define NPOSE 32
#define NLINE 3
#define NBINS 2048
#define CAP 1024
#define ROWW 40

// ---------------------------------------------------------------------------
// Fast f64 exp: |rel err| < ~1e-15 -> rounds to f32 identically to libm exp
// for all practical purposes (mismatch prob ~1e-8/call, and a mismatch is a
// single f32 ulp which only matters on exact rank ties).
// ---------------------------------------------------------------------------
__device__ __forceinline__ double fexp(double x) {
  const double LOG2E = 1.4426950408889634074;
  const double LN2HI = 6.93147180369123816490e-01;
  const double LN2LO = 1.90821492927058770002e-10;
  double kd = rint(x * LOG2E);
  double r = fma(-kd, LN2HI, x);
  r = fma(-kd, LN2LO, r);
  double p = 2.08767569878680989792e-09;     // 1/12!
  p = fma(p, r, 2.50521083854417187751e-08); // 1/11!
  p = fma(p, r, 2.75573192239858906526e-07); // 1/10!
  p = fma(p, r, 2.75573192239858925110e-06); // 1/9!
  p = fma(p, r, 2.48015873015873015873e-05); // 1/8!
  p = fma(p, r, 1.98412698412698412698e-04); // 1/7!
  p = fma(p, r, 1.38888888888888888889e-03); // 1/6!
  p = fma(p, r, 8.33333333333333333333e-03); // 1/5!
  p = fma(p, r, 4.16666666666666666667e-02); // 1/4!
  p = fma(p, r, 1.66666666666666666667e-01); // 1/3!
  p = fma(p, r, 0.5);
  p = fma(p, r, 1.0);
  p = fma(p, r, 1.0);
  return ldexp(p, (int)kd);
}

// ---------------------------------------------------------------------------
// Exact-f32 softmax stats: f32 max; (correctly-rounded) f32 exp of the f32
// difference; numpy pairwise-8 summation order for n=21.
// ---------------------------------------------------------------------------
__device__ __forceinline__ void softmax_es(const float* __restrict__ p, float* e,
                                           float& sumOut) {
  float m = p[0];
#pragma unroll
  for (int c = 1; c < CC; ++c) m = fmaxf(m, p[c]);
#pragma unroll
  for (int c = 0; c < CC; ++c) e[c] = (float)fexp((double)(p[c] - m));
  float r0 = e[0] + e[8], r1 = e[1] + e[9], r2 = e[2] + e[10], r3 = e[3] + e[11];
  float r4 = e[4] + e[12], r5 = e[5] + e[13], r6 = e[6] + e[14], r7 = e[7] + e[15];
  float res = ((r0 + r1) + (r2 + r3)) + ((r4 + r5) + (r6 + r7));
  res += e[16]; res += e[17]; res += e[18]; res += e[19]; res += e[20];
  sumOut = res;
}

// ---------------------------------------------------------------------------
// Mode 2 precompute: scores[b][c][n] (transposed, coalesced per-class reads).
// LDS-staged coalesced input reads; inline fast exp.
// ---------------------------------------------------------------------------
__global__ __launch_bounds__(256) void score_kernel(
    const float* __restrict__ conf, float* __restrict__ scores) {
  __shared__ float buf[256 * CC];
  const int tid = threadIdx.x;
  const int i0 = blockIdx.x * 256;
  const int base = i0 * CC;
  int total = BB * NN * CC - base;
  if (total > 256 * CC) total = 256 * CC;
  for (int t = tid; t < total; t += 256) buf[t] = conf[base + t];
  __syncthreads();
  const int i = i0 + tid;
  if (i >= BB * NN) return;
  const float* p = buf + tid * CC;  // stride 21 (odd): conflict-free-ish
  float e[CC], sum;
  softmax_es(p, e, sum);
  const int b = i / NN, n = i - b * NN;
#pragma unroll
  for (int c = 0; c < CC; ++c)
    scores[((size_t)b * CC + c) * NN + n] = e[c] / sum;
}

// ---------------------------------------------------------------------------
// Mode 1 precompute: aux[b*NN+n] = (max, sum)
// ---------------------------------------------------------------------------
__global__ __launch_bounds__(256) void aux_kernel(
    const float* __restrict__ conf, float2* __restrict__ aux) {
  int i = blockIdx.x * 256 + threadIdx.x;
  if (i >= BB * NN) return;
  const float* p = conf + (size_t)i * CC;
  float e[CC], sum;
  softmax_es(p, e, sum);
  float m = p[0];
#pragma unroll
  for (int c = 1; c < CC; ++c) m = fmaxf(m, p[c]);
  aux[i] = make_float2(m, sum);
}

// ---------------------------------------------------------------------------
// One block per (b,c): exact top-200 + barrier-free wave0 greedy NMS + rows.
// ---------------------------------------------------------------------------
__global__ __launch_bounds__(256) void nms_kernel(
    const float* __restrict__ loc, const float* __restrict__ conf,
    const float* __restrict__ pose, const float* __restrict__ line,
    const float* __restrict__ dbox, const float* __restrict__ scores,
    const float2* __restrict__ aux, int mode, float* __restrict__ out) {
  const int bc = blockIdx.x;
  const int b = bc / CC, c = bc - b * CC;
  const int tid = threadIdx.x;
  float* outSlab = out + (size_t)bc * (TOPK * ROWW);

  // Zero the slab (d_out poisoned 0xAA before every call).
  {
    float4 z = make_float4(0.f, 0.f, 0.f, 0.f);
    float4* o4 = (float4*)outSlab;
    for (int i = tid; i < TOPK * ROWW / 4; i += 256) o4[i] = z;
  }
  if (c == 0) return;  // out.at[:, 0].set(0.0)

  __shared__ int hist[NBINS];
  __shared__ int chunkSum[256];
  __shared__ float cscore[CAP];
  __shared__ int cidx[CAP];
  __shared__ float bx1[TOPK], by1[TOPK], bx2[TOPK], by2[TOPK], barea[TOPK];
  __shared__ int kept[TOPK];
  __shared__ int sBT, sCnt, sKept;

  for (int i = tid; i < NBINS; i += 256) hist[i] = 0;
  if (tid == 0) sCnt = 0;
  __syncthreads();

  const float* scoresB = scores + ((size_t)b * CC + c) * NN;  // mode 2
  const float2* auxB = aux + (size_t)b * NN;                  // mode 1
  const float* confB = conf + (size_t)b * NN * CC + c;

  // ---- pass 1: histogram on f32 score bit-pattern (monotone for s>0) ----
  for (int n = tid; n < NN; n += 256) {
    float s;
    if (mode == 2) {
      s = scoresB[n];
    } else if (mode == 1) {
      float2 a = auxB[n];
      s = (float)fexp((double)(confB[(size_t)n * CC] - a.x)) / a.y;
    } else {
      const float* p = conf + ((size_t)b * NN + n) * CC;
      float e[CC], sum;
      softmax_es(p, e, sum);
      s = e[c] / sum;
    }
    if (s > 0.01f) {
      unsigned u = __float_as_uint(s);
      int bin = (int)(u >> 15) - 30720;
      bin = bin < 0 ? 0 : (bin > NBINS - 1 ? NBINS - 1 : bin);
      atomicAdd(&hist[bin], 1);
    }
  }
  __syncthreads();

  // ---- smallest bin bt whose suffix count >= TOPK ----
  {
    int s8 = 0;
#pragma unroll
    for (int k = 0; k < 8; ++k) s8 += hist[tid * 8 + k];
    chunkSum[tid] = s8;
  }
  __syncthreads();
  if (tid == 0) {
    int cum = 0, bt = 0;
    for (int ch = 255; ch >= 0; --ch) {
      if (cum + chunkSum[ch] >= TOPK) {
        for (int bin = ch * 8 + 7;; --bin) {
          cum += hist[bin];
          if (cum >= TOPK || bin == ch * 8) { bt = bin; break; }
        }
        break;
      }
      cum += chunkSum[ch];
    }
    sBT = bt;
  }
  __syncthreads();
  const int bt = sBT;

  // ---- pass 2: collect candidates (superset of exact top-200) ----
  for (int n = tid; n < NN; n += 256) {
    float s;
    if (mode == 2) {
      s = scoresB[n];
    } else if (mode == 1) {
      float2 a = auxB[n];
      s = (float)fexp((double)(confB[(size_t)n * CC] - a.x)) / a.y;
    } else {
      const float* p = conf + ((size_t)b * NN + n) * CC;
      float e[CC], sum;
      softmax_es(p, e, sum);
      s = e[c] / sum;
    }
    if (s > 0.01f) {
      unsigned u = __float_as_uint(s);
      int bin = (int)(u >> 15) - 30720;
      bin = bin < 0 ? 0 : (bin > NBINS - 1 ? NBINS - 1 : bin);
      if (bin >= bt) {
        int p = atomicAdd(&sCnt, 1);
        if (p < CAP) { cscore[p] = s; cidx[p] = n; }
      }
    }
  }
  __syncthreads();
  const int M = sCnt < CAP ? sCnt : CAP;
  if (M == 0) return;

  // ---- bitonic sort by (score desc, idx asc) — matches lax.top_k ties ----
  int P = 1;
  while (P < M) P <<= 1;
  for (int i = M + tid; i < P; i += 256) {
    cscore[i] = -1e30f;
    cidx[i] = 0x7fffffff;
  }
  __syncthreads();
  for (int k = 2; k <= P; k <<= 1) {
    for (int j = k >> 1; j > 0; j >>= 1) {
      for (int i = tid; i < P; i += 256) {
        int ixj = i ^ j;
        if (ixj > i) {
          float si = cscore[i], sj = cscore[ixj];
          int ii = cidx[i], ij = cidx[ixj];
          bool agt = (si > sj) || (si == sj && ii < ij);  // i ranks before ixj
          bool up = ((i & k) == 0);
          if (up ? !agt : agt) {
            cscore[i] = sj; cscore[ixj] = si;
            cidx[i] = ij;  cidx[ixj] = ii;
          }
        }
      }
      __syncthreads();
    }
  }

  const int K = M < TOPK ? M : TOPK;

  // ---- decode candidate boxes, f32, reference op order (text == R2) ----
  const float* locB = loc + (size_t)b * NN * 4;
  for (int t = tid; t < K; t += 256) {
    int n = cidx[t];
    float l0 = locB[(size_t)n * 4 + 0], l1 = locB[(size_t)n * 4 + 1];
    float l2 = locB[(size_t)n * 4 + 2], l3 = locB[(size_t)n * 4 + 3];
    float d0 = dbox[(size_t)n * 4 + 0], d1 = dbox[(size_t)n * 4 + 1];
    float d2 = dbox[(size_t)n * 4 + 2], d3 = dbox[(size_t)n * 4 + 3];
    float cx = d0 + (l0 * 0.1f) * d2;
    float cy = d1 + (l1 * 0.1f) * d3;
    float w = d2 * (float)fexp((double)(l2 * 0.2f));
    float h = d3 * (float)fexp((double)(l3 * 0.2f));
    float x1 = cx - w * 0.5f;
    float y1 = cy - h * 0.5f;
    float x2 = x1 + w;
    float y2 = y1 + h;
    bx1[t] = x1; by1[t] = y1; bx2[t] = x2; by2[t] = y2;
    barea[t] = (x2 - x1) * (y2 - y1);
  }
  __syncthreads();

  // ---- barrier-free greedy NMS on wave 0 (64 lanes x 4 slots, registers) ----
  if (tid < 64) {
    const int lane = tid;
    float X1[4], Y1[4], X2[4], Y2[4], AR[4];
    unsigned aliveBits = 0;
#pragma unroll
    for (int s = 0; s < 4; ++s) {
      int l = s * 64 + lane;
      if (l < K) {
        X1[s] = bx1[l]; Y1[s] = by1[l]; X2[s] = bx2[l]; Y2[s] = by2[l];
        AR[s] = barea[l];
        aliveBits |= 1u << s;
      } else {
        X1[s] = 0.f; Y1[s] = 0.f; X2[s] = 0.f; Y2[s] = 0.f; AR[s] = 0.f;
      }
    }
#pragma unroll
    for (int s = 0; s < 4; ++s) {
      int jmax = K - s * 64;
      if (jmax > 64) jmax = 64;
      for (int jj = 0; jj < jmax; ++jj) {
        unsigned abits = (unsigned)__shfl((int)aliveBits, jj, 64);
        if (!((abits >> s) & 1)) continue;  // wave-uniform
        const int j = s * 64 + jj;
        float x1j = __shfl(X1[s], jj, 64);
        float y1j = __shfl(Y1[s], jj, 64);
        float x2j = __shfl(X2[s], jj, 64);
        float y2j = __shfl(Y2[s], jj, 64);
        float aj  = __shfl(AR[s], jj, 64);
#pragma unroll
        for (int t2 = 0; t2 < 4; ++t2) {
          int l = t2 * 64 + lane;
          if (((aliveBits >> t2) & 1) && l > j) {
            float xx1 = fmaxf(X1[t2], x1j);
            float yy1 = fmaxf(Y1[t2], y1j);
            float xx2 = fminf(X2[t2], x2j);
            float yy2 = fminf(Y2[t2], y2j);
            float iw = fmaxf(xx2 - xx1, 0.0f);
            float ih = fmaxf(yy2 - yy1, 0.0f);
            float inter = iw * ih;
            float uni = (AR[t2] - inter) + aj;  // area - inter + area[i]
            if (inter / uni > 0.45f) aliveBits &= ~(1u << t2);
          }
        }
      }
    }
    // compact kept indices (ascending j == sorted order == output row order)
    int base2 = 0;
#pragma unroll
    for (int s = 0; s < 4; ++s) {
      unsigned long long mb = __ballot((int)((aliveBits >> s) & 1));
      if ((aliveBits >> s) & 1) {
        int rank = base2 + __popcll(mb & ((1ull << lane) - 1));
        kept[rank] = s * 64 + lane;
      }
      base2 += __popcll(mb);
    }
    if (lane == 0) sKept = base2;
  }
  __syncthreads();

  // ---- write kept rows: [score, box4, pose32, line3] ----
  const int nk = sKept;
  const float* poseB = pose + (size_t)b * NN * NPOSE;
  const float* lineB = line + (size_t)b * NN * NLINE;
  for (int t = tid; t < nk; t += 256) {
    int j = kept[t];
    int n = cidx[j];
    float* row = outSlab + (size_t)t * ROWW;
    row[0] = cscore[j];
    row[1] = bx1[j];
    row[2] = by1[j];
    row[3] = bx2[j];
    row[4] = by2[j];
#pragma unroll
    for (int q = 0; q < NPOSE; ++q) row[5 + q] = poseB[(size_t)n * NPOSE + q];
    row[37] = lineB[(size_t)n * NLINE + 0];
    row[38] = lineB[(size_t)n * NLINE + 1];
    row[39] = lineB[(size_t)n * NLINE + 2];
  }
}

// ---------------------------------------------------------------------------
extern "C" void kernel_launch(void* const* d_in, const int* in_sizes, int n_in,
                              void* d_out, int out_size, void* d_ws, size_t ws_size,
                              hipStream_t stream) {
  const float* loc  = (const float*)d_in[0];
  const float* conf = (const float*)d_in[1];
  const float* pose = (const float*)d_in[2];
  const float* line = (const float*)d_in[3];
  const float* dbox = (const float*)d_in[4];
  float* out = (float*)d_out;

  const size_t scoreBytes = (size_t)BB * CC * NN * sizeof(float);   // ~23.5 MB
  const size_t auxBytes   = (size_t)BB * NN * sizeof(float2);       // ~2.2 MB

  int mode;
  float* scores = nullptr;
  float2* aux = nullptr;
  if (ws_size >= scoreBytes) {
    mode = 2; scores = (float*)d_ws;
  } else if (ws_size >= auxBytes) {
    mode = 1; aux = (float2*)d_ws;
  } else {
    mode = 0;
  }

  const int total = BB * NN;
  if (mode == 2) {
    score_kernel<<<(total + 255) / 256, 256, 0, stream>>>(conf, scores);
  } else if (mode == 1) {
    aux_kernel<<<(total + 255) / 256, 256, 0, stream>>>(conf, aux);
  }
  nms_kernel<<<BB * CC, 256, 0, stream>>>(loc, conf, pose, line, dbox,
                                          scores, aux, mode, out);
}

// Round 4
// 191.999 us; speedup vs baseline: 1.0643x; 1.0643x over previous
//
#include <hip/hip_runtime.h>
#include <math.h>

#define BB 32
#define NN 8732
#define CC 21
#define TOPK 200
#define NPOSE 32
#define NLINE 3
#define NBINS 2048
#define CAP 1024
#define ROWW 40

// ---------------------------------------------------------------------------
// Fast f64 exp, |rel err| ~1e-15: rounds to f32 identically to libm exp except
// with probability ~2e-8/call (1-ulp, matters only on exact rank ties).
// ldexp replaced by exact power-of-two multiply (bit-identical, k in [-75,2]).
// ---------------------------------------------------------------------------
__device__ __forceinline__ double fexp(double x) {
  const double LOG2E = 1.4426950408889634074;
  const double LN2HI = 6.93147180369123816490e-01;
  const double LN2LO = 1.90821492927058770002e-10;
  double kd = rint(x * LOG2E);
  double r = fma(-kd, LN2HI, x);
  r = fma(-kd, LN2LO, r);
  double p = 2.08767569878680989792e-09;     // 1/12!
  p = fma(p, r, 2.50521083854417187751e-08); // 1/11!
  p = fma(p, r, 2.75573192239858906526e-07); // 1/10!
  p = fma(p, r, 2.75573192239858925110e-06); // 1/9!
  p = fma(p, r, 2.48015873015873015873e-05); // 1/8!
  p = fma(p, r, 1.98412698412698412698e-04); // 1/7!
  p = fma(p, r, 1.38888888888888888889e-03); // 1/6!
  p = fma(p, r, 8.33333333333333333333e-03); // 1/5!
  p = fma(p, r, 4.16666666666666666667e-02); // 1/4!
  p = fma(p, r, 1.66666666666666666667e-01); // 1/3!
  p = fma(p, r, 0.5);
  p = fma(p, r, 1.0);
  p = fma(p, r, 1.0);
  int k = (int)kd;
  k = k < -1020 ? -1020 : (k > 1020 ? 1020 : k);
  double sc = __longlong_as_double((long long)(1023 + k) << 52);
  return p * sc;  // exact pow2 multiply == ldexp(p,k)
}

// ---------------------------------------------------------------------------
// scores[b][c][n] = softmax(conf)[b][n][c], exact-f32 pipeline:
// f32 max; f32-rounded exp of f32 diff; numpy pairwise-8 sum; true f32 div.
// LDS round-trip + unroll-1 keeps VGPR pressure (and spills) down.
// ---------------------------------------------------------------------------
__global__ __launch_bounds__(256) void score_kernel(
    const float* __restrict__ conf, float* __restrict__ scores) {
  __shared__ __align__(16) float buf[256 * CC];
  const int tid = threadIdx.x;
  const int i0 = blockIdx.x * 256;
  const int base = i0 * CC;
  int total = BB * NN * CC - base;
  if (total > 256 * CC) total = 256 * CC;
  // total and base are multiples of 4 for every block -> float4 staging
  {
    const float4* g4 = (const float4*)(conf + base);
    float4* b4 = (float4*)buf;
    const int n4 = total >> 2;
    for (int t = tid; t < n4; t += 256) b4[t] = g4[t];
  }
  __syncthreads();
  const int i = i0 + tid;
  if (i >= BB * NN) return;
  float* p = buf + tid * CC;  // stride 21 (odd) -> 2-way LDS aliasing = free
  float m = p[0];
#pragma unroll
  for (int c = 1; c < CC; ++c) m = fmaxf(m, p[c]);
#pragma unroll 1
  for (int c = 0; c < CC; ++c) p[c] = (float)fexp((double)(p[c] - m));
  float r0 = p[0] + p[8], r1 = p[1] + p[9], r2 = p[2] + p[10], r3 = p[3] + p[11];
  float r4 = p[4] + p[12], r5 = p[5] + p[13], r6 = p[6] + p[14], r7 = p[7] + p[15];
  float sum = ((r0 + r1) + (r2 + r3)) + ((r4 + r5) + (r6 + r7));
  sum += p[16]; sum += p[17]; sum += p[18]; sum += p[19]; sum += p[20];
  const int b = i / NN, n = i - b * NN;
#pragma unroll 1
  for (int c = 0; c < CC; ++c)
    scores[((size_t)b * CC + c) * NN + n] = p[c] / sum;  // true f32 divide
}

// ---------------------------------------------------------------------------
// Mode 1 fallback: aux[b*NN+n] = (max, sum)
// ---------------------------------------------------------------------------
__global__ __launch_bounds__(256) void aux_kernel(
    const float* __restrict__ conf, float2* __restrict__ aux) {
  int i = blockIdx.x * 256 + threadIdx.x;
  if (i >= BB * NN) return;
  const float* p = conf + (size_t)i * CC;
  float m = p[0];
#pragma unroll
  for (int c = 1; c < CC; ++c) m = fmaxf(m, p[c]);
  float e[CC];
#pragma unroll 1
  for (int c = 0; c < CC; ++c) e[c] = (float)fexp((double)(p[c] - m));
  float r0 = e[0] + e[8], r1 = e[1] + e[9], r2 = e[2] + e[10], r3 = e[3] + e[11];
  float r4 = e[4] + e[12], r5 = e[5] + e[13], r6 = e[6] + e[14], r7 = e[7] + e[15];
  float sum = ((r0 + r1) + (r2 + r3)) + ((r4 + r5) + (r6 + r7));
  sum += e[16]; sum += e[17]; sum += e[18]; sum += e[19]; sum += e[20];
  aux[i] = make_float2(m, sum);
}

__device__ __forceinline__ int score_bin(float s) {
  unsigned u = __float_as_uint(s);
  int bin = (int)(u >> 15) - 30720;
  return bin < 0 ? 0 : (bin > NBINS - 1 ? NBINS - 1 : bin);
}

// ---------------------------------------------------------------------------
// One block per (b,c): single-pass register-resident top-200 selection +
// wave0 shuffle NMS + row assembly. Mode 2 (precomputed scores) is the
// fast path: 9 independent float4 loads per thread, no second global pass.
// ---------------------------------------------------------------------------
__global__ __launch_bounds__(256) void nms_kernel(
    const float* __restrict__ loc, const float* __restrict__ conf,
    const float* __restrict__ pose, const float* __restrict__ line,
    const float* __restrict__ dbox, const float* __restrict__ scores,
    const float2* __restrict__ aux, int mode, float* __restrict__ out) {
  const int bc = blockIdx.x;
  const int b = bc / CC, c = bc - b * CC;
  const int tid = threadIdx.x;
  float* outSlab = out + (size_t)bc * (TOPK * ROWW);

  // Zero the slab (d_out poisoned 0xAA before every call).
  {
    float4 z = make_float4(0.f, 0.f, 0.f, 0.f);
    float4* o4 = (float4*)outSlab;
    for (int i = tid; i < TOPK * ROWW / 4; i += 256) o4[i] = z;
  }
  if (c == 0) return;  // out.at[:, 0].set(0.0)

  __shared__ int hist[NBINS];
  __shared__ int chunkSum[256];
  __shared__ float cscore[CAP];
  __shared__ int cidx[CAP];
  __shared__ float bx1[TOPK], by1[TOPK], bx2[TOPK], by2[TOPK], barea[TOPK];
  __shared__ int kept[TOPK];
  __shared__ int sBT, sCnt, sKept;

  for (int i = tid; i < NBINS; i += 256) hist[i] = 0;
  if (tid == 0) sCnt = 0;
  __syncthreads();

  const float* scoresB = scores + ((size_t)b * CC + c) * NN;  // mode 2
  const float2* auxB = aux + (size_t)b * NN;                  // mode 1
  const float* confB = conf + (size_t)b * NN * CC + c;

  if (mode == 2) {
    // ---- single pass: 9 independent float4 loads -> registers ----
    float4 v[9];
#pragma unroll
    for (int k = 0; k < 8; ++k)
      v[k] = *(const float4*)(scoresB + k * 1024 + tid * 4);
    if (tid < 135)  // 8732 - 8192 = 540 = 135*4 -> exact tail
      v[8] = *(const float4*)(scoresB + 8192 + tid * 4);
    else
      v[8] = make_float4(-1.f, -1.f, -1.f, -1.f);

    // histogram from registers
#pragma unroll
    for (int k = 0; k < 9; ++k) {
      float s0 = v[k].x, s1 = v[k].y, s2 = v[k].z, s3 = v[k].w;
      if (s0 > 0.01f) atomicAdd(&hist[score_bin(s0)], 1);
      if (s1 > 0.01f) atomicAdd(&hist[score_bin(s1)], 1);
      if (s2 > 0.01f) atomicAdd(&hist[score_bin(s2)], 1);
      if (s3 > 0.01f) atomicAdd(&hist[score_bin(s3)], 1);
    }
    __syncthreads();

    // threshold bin
    {
      int s8 = 0;
#pragma unroll
      for (int k = 0; k < 8; ++k) s8 += hist[tid * 8 + k];
      chunkSum[tid] = s8;
    }
    __syncthreads();
    if (tid == 0) {
      int cum = 0, bt = 0;
      for (int ch = 255; ch >= 0; --ch) {
        if (cum + chunkSum[ch] >= TOPK) {
          for (int bin = ch * 8 + 7;; --bin) {
            cum += hist[bin];
            if (cum >= TOPK || bin == ch * 8) { bt = bin; break; }
          }
          break;
        }
        cum += chunkSum[ch];
      }
      sBT = bt;
    }
    __syncthreads();
    const int bt = sBT;

    // collect candidates from registers (no second global pass)
#pragma unroll
    for (int k = 0; k < 9; ++k) {
      float sv[4] = {v[k].x, v[k].y, v[k].z, v[k].w};
#pragma unroll
      for (int j = 0; j < 4; ++j) {
        float s = sv[j];
        if (s > 0.01f && score_bin(s) >= bt) {
          int p = atomicAdd(&sCnt, 1);
          if (p < CAP) { cscore[p] = s; cidx[p] = k * 1024 + tid * 4 + j; }
        }
      }
    }
  } else {
    // ---- fallback scalar two-pass (modes 0/1) ----
    for (int n = tid; n < NN; n += 256) {
      float s;
      if (mode == 1) {
        float2 a = auxB[n];
        s = (float)fexp((double)(confB[(size_t)n * CC] - a.x)) / a.y;
      } else {
        const float* p = conf + ((size_t)b * NN + n) * CC;
        float mm = p[0];
        for (int c2 = 1; c2 < CC; ++c2) mm = fmaxf(mm, p[c2]);
        float e[CC];
        for (int c2 = 0; c2 < CC; ++c2) e[c2] = (float)fexp((double)(p[c2] - mm));
        float r0 = e[0] + e[8], r1 = e[1] + e[9], r2 = e[2] + e[10], r3 = e[3] + e[11];
        float r4 = e[4] + e[12], r5 = e[5] + e[13], r6 = e[6] + e[14], r7 = e[7] + e[15];
        float sum = ((r0 + r1) + (r2 + r3)) + ((r4 + r5) + (r6 + r7));
        sum += e[16]; sum += e[17]; sum += e[18]; sum += e[19]; sum += e[20];
        s = e[c] / sum;
      }
      if (s > 0.01f) atomicAdd(&hist[score_bin(s)], 1);
    }
    __syncthreads();
    {
      int s8 = 0;
#pragma unroll
      for (int k = 0; k < 8; ++k) s8 += hist[tid * 8 + k];
      chunkSum[tid] = s8;
    }
    __syncthreads();
    if (tid == 0) {
      int cum = 0, bt = 0;
      for (int ch = 255; ch >= 0; --ch) {
        if (cum + chunkSum[ch] >= TOPK) {
          for (int bin = ch * 8 + 7;; --bin) {
            cum += hist[bin];
            if (cum >= TOPK || bin == ch * 8) { bt = bin; break; }
          }
          break;
        }
        cum += chunkSum[ch];
      }
      sBT = bt;
    }
    __syncthreads();
    const int bt = sBT;
    for (int n = tid; n < NN; n += 256) {
      float s;
      if (mode == 1) {
        float2 a = auxB[n];
        s = (float)fexp((double)(confB[(size_t)n * CC] - a.x)) / a.y;
      } else {
        const float* p = conf + ((size_t)b * NN + n) * CC;
        float mm = p[0];
        for (int c2 = 1; c2 < CC; ++c2) mm = fmaxf(mm, p[c2]);
        float e[CC];
        for (int c2 = 0; c2 < CC; ++c2) e[c2] = (float)fexp((double)(p[c2] - mm));
        float r0 = e[0] + e[8], r1 = e[1] + e[9], r2 = e[2] + e[10], r3 = e[3] + e[11];
        float r4 = e[4] + e[12], r5 = e[5] + e[13], r6 = e[6] + e[14], r7 = e[7] + e[15];
        float sum = ((r0 + r1) + (r2 + r3)) + ((r4 + r5) + (r6 + r7));
        sum += e[16]; sum += e[17]; sum += e[18]; sum += e[19]; sum += e[20];
        s = e[c] / sum;
      }
      if (s > 0.01f && score_bin(s) >= bt) {
        int p = atomicAdd(&sCnt, 1);
        if (p < CAP) { cscore[p] = s; cidx[p] = n; }
      }
    }
  }
  __syncthreads();
  const int M = sCnt < CAP ? sCnt : CAP;
  if (M == 0) return;

  // ---- bitonic sort by (score desc, idx asc) — matches lax.top_k ties ----
  int P = 1;
  while (P < M) P <<= 1;
  for (int i = M + tid; i < P; i += 256) {
    cscore[i] = -1e30f;
    cidx[i] = 0x7fffffff;
  }
  __syncthreads();
  for (int k = 2; k <= P; k <<= 1) {
    for (int j = k >> 1; j > 0; j >>= 1) {
      for (int i = tid; i < P; i += 256) {
        int ixj = i ^ j;
        if (ixj > i) {
          float si = cscore[i], sj = cscore[ixj];
          int ii = cidx[i], ij = cidx[ixj];
          bool agt = (si > sj) || (si == sj && ii < ij);
          bool up = ((i & k) == 0);
          if (up ? !agt : agt) {
            cscore[i] = sj; cscore[ixj] = si;
            cidx[i] = ij;  cidx[ixj] = ii;
          }
        }
      }
      __syncthreads();
    }
  }

  const int K = M < TOPK ? M : TOPK;

  // ---- decode candidate boxes, f32, reference op order ----
  const float* locB = loc + (size_t)b * NN * 4;
  for (int t = tid; t < K; t += 256) {
    int n = cidx[t];
    float l0 = locB[(size_t)n * 4 + 0], l1 = locB[(size_t)n * 4 + 1];
    float l2 = locB[(size_t)n * 4 + 2], l3 = locB[(size_t)n * 4 + 3];
    float d0 = dbox[(size_t)n * 4 + 0], d1 = dbox[(size_t)n * 4 + 1];
    float d2 = dbox[(size_t)n * 4 + 2], d3 = dbox[(size_t)n * 4 + 3];
    float cx = d0 + (l0 * 0.1f) * d2;
    float cy = d1 + (l1 * 0.1f) * d3;
    float w = d2 * (float)fexp((double)(l2 * 0.2f));
    float h = d3 * (float)fexp((double)(l3 * 0.2f));
    float x1 = cx - w * 0.5f;
    float y1 = cy - h * 0.5f;
    float x2 = x1 + w;
    float y2 = y1 + h;
    bx1[t] = x1; by1[t] = y1; bx2[t] = x2; by2[t] = y2;
    barea[t] = (x2 - x1) * (y2 - y1);
  }
  __syncthreads();

  // ---- barrier-free greedy NMS on wave 0 (registers + shuffles) ----
  if (tid < 64) {
    const int lane = tid;
    float X1[4], Y1[4], X2[4], Y2[4], AR[4];
    unsigned aliveBits = 0;
#pragma unroll
    for (int s = 0; s < 4; ++s) {
      int l = s * 64 + lane;
      if (l < K) {
        X1[s] = bx1[l]; Y1[s] = by1[l]; X2[s] = bx2[l]; Y2[s] = by2[l];
        AR[s] = barea[l];
        aliveBits |= 1u << s;
      } else {
        X1[s] = 0.f; Y1[s] = 0.f; X2[s] = 0.f; Y2[s] = 0.f; AR[s] = 0.f;
      }
    }
#pragma unroll
    for (int s = 0; s < 4; ++s) {
      int jmax = K - s * 64;
      if (jmax > 64) jmax = 64;
      for (int jj = 0; jj < jmax; ++jj) {
        unsigned abits = (unsigned)__shfl((int)aliveBits, jj, 64);
        if (!((abits >> s) & 1)) continue;  // wave-uniform
        const int j = s * 64 + jj;
        float x1j = __shfl(X1[s], jj, 64);
        float y1j = __shfl(Y1[s], jj, 64);
        float x2j = __shfl(X2[s], jj, 64);
        float y2j = __shfl(Y2[s], jj, 64);
        float aj  = __shfl(AR[s], jj, 64);
#pragma unroll
        for (int t2 = 0; t2 < 4; ++t2) {
          int l = t2 * 64 + lane;
          if (((aliveBits >> t2) & 1) && l > j) {
            float xx1 = fmaxf(X1[t2], x1j);
            float yy1 = fmaxf(Y1[t2], y1j);
            float xx2 = fminf(X2[t2], x2j);
            float yy2 = fminf(Y2[t2], y2j);
            float iw = fmaxf(xx2 - xx1, 0.0f);
            float ih = fmaxf(yy2 - yy1, 0.0f);
            float inter = iw * ih;
            float uni = (AR[t2] - inter) + aj;
            if (inter / uni > 0.45f) aliveBits &= ~(1u << t2);
          }
        }
      }
    }
    int base2 = 0;
#pragma unroll
    for (int s = 0; s < 4; ++s) {
      unsigned long long mb = __ballot((int)((aliveBits >> s) & 1));
      if ((aliveBits >> s) & 1) {
        int rank = base2 + __popcll(mb & ((1ull << lane) - 1));
        kept[rank] = s * 64 + lane;
      }
      base2 += __popcll(mb);
    }
    if (lane == 0) sKept = base2;
  }
  __syncthreads();

  // ---- write kept rows: [score, box4, pose32, line3] ----
  const int nk = sKept;
  const float* poseB = pose + (size_t)b * NN * NPOSE;
  const float* lineB = line + (size_t)b * NN * NLINE;
  for (int t = tid; t < nk; t += 256) {
    int j = kept[t];
    int n = cidx[j];
    float* row = outSlab + (size_t)t * ROWW;
    row[0] = cscore[j];
    row[1] = bx1[j];
    row[2] = by1[j];
    row[3] = bx2[j];
    row[4] = by2[j];
    const float4* p4 = (const float4*)(poseB + (size_t)n * NPOSE);  // 128B aligned
#pragma unroll
    for (int q = 0; q < 8; ++q) {
      float4 pv = p4[q];
      row[5 + 4 * q + 0] = pv.x;
      row[5 + 4 * q + 1] = pv.y;
      row[5 + 4 * q + 2] = pv.z;
      row[5 + 4 * q + 3] = pv.w;
    }
    row[37] = lineB[(size_t)n * NLINE + 0];
    row[38] = lineB[(size_t)n * NLINE + 1];
    row[39] = lineB[(size_t)n * NLINE + 2];
  }
}

// ---------------------------------------------------------------------------
extern "C" void kernel_launch(void* const* d_in, const int* in_sizes, int n_in,
                              void* d_out, int out_size, void* d_ws, size_t ws_size,
                              hipStream_t stream) {
  const float* loc  = (const float*)d_in[0];
  const float* conf = (const float*)d_in[1];
  const float* pose = (const float*)d_in[2];
  const float* line = (const float*)d_in[3];
  const float* dbox = (const float*)d_in[4];
  float* out = (float*)d_out;

  const size_t scoreBytes = (size_t)BB * CC * NN * sizeof(float);   // ~23.5 MB
  const size_t auxBytes   = (size_t)BB * NN * sizeof(float2);       // ~2.2 MB

  int mode;
  float* scores = nullptr;
  float2* aux = nullptr;
  if (ws_size >= scoreBytes) {
    mode = 2; scores = (float*)d_ws;
  } else if (ws_size >= auxBytes) {
    mode = 1; aux = (float2*)d_ws;
  } else {
    mode = 0;
  }

  const int total = BB * NN;
  if (mode == 2) {
    score_kernel<<<(total + 255) / 256, 256, 0, stream>>>(conf, scores);
  } else if (mode == 1) {
    aux_kernel<<<(total + 255) / 256, 256, 0, stream>>>(conf, aux);
  }
  nms_kernel<<<BB * CC, 256, 0, stream>>>(loc, conf, pose, line, dbox,
                                          scores, aux, mode, out);
}

// Round 5
// 187.093 us; speedup vs baseline: 1.0922x; 1.0262x over previous
//
#include <hip/hip_runtime.h>
#include <math.h>

#define BB 32
#define NN 8732
#define CC 21
#define TOPK 200
#define NPOSE 32
#define NLINE 3
#define NBINS 2048
#define CAP 1024
#define ROWW 40

// ---------------------------------------------------------------------------
// Fast f64 exp, |rel err| ~1e-15: f32-rounds identically to libm exp except
// with prob ~2e-8/call (1 ulp, matters only on exact rank ties).
// ---------------------------------------------------------------------------
__device__ __forceinline__ double fexp(double x) {
  const double LOG2E = 1.4426950408889634074;
  const double LN2HI = 6.93147180369123816490e-01;
  const double LN2LO = 1.90821492927058770002e-10;
  double kd = rint(x * LOG2E);
  double r = fma(-kd, LN2HI, x);
  r = fma(-kd, LN2LO, r);
  double p = 2.08767569878680989792e-09;
  p = fma(p, r, 2.50521083854417187751e-08);
  p = fma(p, r, 2.75573192239858906526e-07);
  p = fma(p, r, 2.75573192239858925110e-06);
  p = fma(p, r, 2.48015873015873015873e-05);
  p = fma(p, r, 1.98412698412698412698e-04);
  p = fma(p, r, 1.38888888888888888889e-03);
  p = fma(p, r, 8.33333333333333333333e-03);
  p = fma(p, r, 4.16666666666666666667e-02);
  p = fma(p, r, 1.66666666666666666667e-01);
  p = fma(p, r, 0.5);
  p = fma(p, r, 1.0);
  p = fma(p, r, 1.0);
  int k = (int)kd;
  k = k < -1020 ? -1020 : (k > 1020 ? 1020 : k);
  double sc = __longlong_as_double((long long)(1023 + k) << 52);
  return p * sc;  // exact pow2 mul == ldexp(p,k)
}

// ---------------------------------------------------------------------------
// scores[b][c][n] = softmax(conf)[b][n][c]; exact-f32 pipeline (f32 max,
// f32-rounded exp of f32 diff, numpy pairwise-8 sum, true f32 divide).
// Full-register exps: 21 independent chains, no LDS round-trip.
// ---------------------------------------------------------------------------
__global__ __launch_bounds__(256, 4) void score_kernel(
    const float* __restrict__ conf, float* __restrict__ scores) {
  __shared__ __align__(16) float buf[256 * CC];
  const int tid = threadIdx.x;
  const int i0 = blockIdx.x * 256;
  const int base = i0 * CC;
  int total = BB * NN * CC - base;
  if (total > 256 * CC) total = 256 * CC;
  {
    const float4* g4 = (const float4*)(conf + base);
    float4* b4 = (float4*)buf;
    const int n4 = total >> 2;
    for (int t = tid; t < n4; t += 256) b4[t] = g4[t];
  }
  __syncthreads();
  const int i = i0 + tid;
  if (i >= BB * NN) return;
  const float* p = buf + tid * CC;
  float x[CC];
#pragma unroll
  for (int c = 0; c < CC; ++c) x[c] = p[c];
  float m = x[0];
#pragma unroll
  for (int c = 1; c < CC; ++c) m = fmaxf(m, x[c]);
  float e[CC];
#pragma unroll
  for (int c = 0; c < CC; ++c) e[c] = (float)fexp((double)(x[c] - m));
  float r0 = e[0] + e[8], r1 = e[1] + e[9], r2 = e[2] + e[10], r3 = e[3] + e[11];
  float r4 = e[4] + e[12], r5 = e[5] + e[13], r6 = e[6] + e[14], r7 = e[7] + e[15];
  float sum = ((r0 + r1) + (r2 + r3)) + ((r4 + r5) + (r6 + r7));
  sum += e[16]; sum += e[17]; sum += e[18]; sum += e[19]; sum += e[20];
  const int b = i / NN, n = i - b * NN;
#pragma unroll
  for (int c = 0; c < CC; ++c)
    scores[((size_t)b * CC + c) * NN + n] = e[c] / sum;  // true f32 divide
}

// ---------------------------------------------------------------------------
// Mode 1 fallback: aux[b*NN+n] = (max, sum)
// ---------------------------------------------------------------------------
__global__ __launch_bounds__(256) void aux_kernel(
    const float* __restrict__ conf, float2* __restrict__ aux) {
  int i = blockIdx.x * 256 + threadIdx.x;
  if (i >= BB * NN) return;
  const float* p = conf + (size_t)i * CC;
  float m = p[0];
#pragma unroll
  for (int c = 1; c < CC; ++c) m = fmaxf(m, p[c]);
  float e[CC];
#pragma unroll 1
  for (int c = 0; c < CC; ++c) e[c] = (float)fexp((double)(p[c] - m));
  float r0 = e[0] + e[8], r1 = e[1] + e[9], r2 = e[2] + e[10], r3 = e[3] + e[11];
  float r4 = e[4] + e[12], r5 = e[5] + e[13], r6 = e[6] + e[14], r7 = e[7] + e[15];
  float sum = ((r0 + r1) + (r2 + r3)) + ((r4 + r5) + (r6 + r7));
  sum += e[16]; sum += e[17]; sum += e[18]; sum += e[19]; sum += e[20];
  aux[i] = make_float2(m, sum);
}

__device__ __forceinline__ int score_bin(float s) {
  unsigned u = __float_as_uint(s);
  int bin = (int)(u >> 15) - 30720;
  return bin < 0 ? 0 : (bin > NBINS - 1 ? NBINS - 1 : bin);
}

// Fallback scalar score for modes 0/1
__device__ __forceinline__ float score_at(int mode, int b, int c, int n,
                                          const float* conf, const float2* auxB,
                                          const float* confB) {
  if (mode == 1) {
    float2 a = auxB[n];
    return (float)fexp((double)(confB[(size_t)n * CC] - a.x)) / a.y;
  }
  const float* p = conf + ((size_t)b * NN + n) * CC;
  float mm = p[0];
  for (int c2 = 1; c2 < CC; ++c2) mm = fmaxf(mm, p[c2]);
  float e[CC];
  for (int c2 = 0; c2 < CC; ++c2) e[c2] = (float)fexp((double)(p[c2] - mm));
  float r0 = e[0] + e[8], r1 = e[1] + e[9], r2 = e[2] + e[10], r3 = e[3] + e[11];
  float r4 = e[4] + e[12], r5 = e[5] + e[13], r6 = e[6] + e[14], r7 = e[7] + e[15];
  float sum = ((r0 + r1) + (r2 + r3)) + ((r4 + r5) + (r6 + r7));
  sum += e[16]; sum += e[17]; sum += e[18]; sum += e[19]; sum += e[20];
  return e[c] / sum;
}

// ---------------------------------------------------------------------------
// One block per (b,c): single-pass top-200 + parallel IoU matrix + short
// serial greedy bit-scan + row assembly.
// ---------------------------------------------------------------------------
__global__ __launch_bounds__(256) void nms_kernel(
    const float* __restrict__ loc, const float* __restrict__ conf,
    const float* __restrict__ pose, const float* __restrict__ line,
    const float* __restrict__ dbox, const float* __restrict__ scores,
    const float2* __restrict__ aux, int mode, float* __restrict__ out) {
  const int bc = blockIdx.x;
  const int b = bc / CC, c = bc - b * CC;
  const int tid = threadIdx.x;
  const int wv = tid >> 6, lane = tid & 63;
  float* outSlab = out + (size_t)bc * (TOPK * ROWW);
  const float4 z4 = make_float4(0.f, 0.f, 0.f, 0.f);

  if (c == 0) {  // out.at[:, 0].set(0.0)
    float4* o4 = (float4*)outSlab;
    for (int i = tid; i < TOPK * ROWW / 4; i += 256) o4[i] = z4;
    return;
  }

  __shared__ int hist[NBINS];
  __shared__ float cscore[CAP];
  __shared__ int cidx[CAP];
  __shared__ float bx1[TOPK], by1[TOPK], bx2[TOPK], by2[TOPK], barea[TOPK];
  __shared__ unsigned long long supp[TOPK * 4];  // IoU>thr bits, l>j only
  __shared__ int kept[TOPK];
  __shared__ int waveTot[4];
  __shared__ int sBT, sCnt, sKept;

  for (int i = tid; i < NBINS; i += 256) hist[i] = 0;
  if (tid == 0) { sCnt = 0; sBT = 0; }
  __syncthreads();

  const float* scoresB = scores + ((size_t)b * CC + c) * NN;
  const float2* auxB = aux + (size_t)b * NN;
  const float* confB = conf + (size_t)b * NN * CC + c;

  float4 v[9];
  if (mode == 2) {
    // ---- single pass: 9 independent float4 loads -> registers ----
#pragma unroll
    for (int k = 0; k < 8; ++k)
      v[k] = *(const float4*)(scoresB + k * 1024 + tid * 4);
    if (tid < 135)  // 8732-8192=540=135*4
      v[8] = *(const float4*)(scoresB + 8192 + tid * 4);
    else
      v[8] = make_float4(-1.f, -1.f, -1.f, -1.f);
#pragma unroll
    for (int k = 0; k < 9; ++k) {
      if (v[k].x > 0.01f) atomicAdd(&hist[score_bin(v[k].x)], 1);
      if (v[k].y > 0.01f) atomicAdd(&hist[score_bin(v[k].y)], 1);
      if (v[k].z > 0.01f) atomicAdd(&hist[score_bin(v[k].z)], 1);
      if (v[k].w > 0.01f) atomicAdd(&hist[score_bin(v[k].w)], 1);
    }
  } else {
    for (int n = tid; n < NN; n += 256) {
      float s = score_at(mode, b, c, n, conf, auxB, confB);
      if (s > 0.01f) atomicAdd(&hist[score_bin(s)], 1);
    }
  }
  __syncthreads();

  // ---- parallel threshold-bin: wave shuffle suffix-scan + crossing thread --
  int s8 = 0;
#pragma unroll
  for (int k = 0; k < 8; ++k) s8 += hist[tid * 8 + k];
  int cs = s8;  // inclusive suffix within wave (by lane)
#pragma unroll
  for (int d = 1; d < 64; d <<= 1) {
    int t = __shfl_down(cs, d, 64);
    if (lane + d < 64) cs += t;
  }
  if (lane == 0) waveTot[wv] = cs;
  __syncthreads();
  {
    int higher = 0;
    for (int g = wv + 1; g < 4; ++g) higher += waveTot[g];
    int incl = cs + higher;       // sum over chunks >= tid
    int excl = incl - s8;         // sum over chunks >  tid
    if (excl < TOPK && incl >= TOPK) {  // unique crossing thread
      int cum = excl, bt = tid * 8;
      for (int bin = tid * 8 + 7;; --bin) {
        cum += hist[bin];
        if (cum >= TOPK || bin == tid * 8) { bt = bin; break; }
      }
      sBT = bt;
    }
  }
  __syncthreads();
  const int bt = sBT;

  // ---- collect candidates ----
  if (mode == 2) {
#pragma unroll
    for (int k = 0; k < 9; ++k) {
      float sv[4] = {v[k].x, v[k].y, v[k].z, v[k].w};
#pragma unroll
      for (int j = 0; j < 4; ++j) {
        float s = sv[j];
        if (s > 0.01f && score_bin(s) >= bt) {
          int p = atomicAdd(&sCnt, 1);
          if (p < CAP) { cscore[p] = s; cidx[p] = k * 1024 + tid * 4 + j; }
        }
      }
    }
  } else {
    for (int n = tid; n < NN; n += 256) {
      float s = score_at(mode, b, c, n, conf, auxB, confB);
      if (s > 0.01f && score_bin(s) >= bt) {
        int p = atomicAdd(&sCnt, 1);
        if (p < CAP) { cscore[p] = s; cidx[p] = n; }
      }
    }
  }
  __syncthreads();
  const int M = sCnt < CAP ? sCnt : CAP;
  if (M == 0) {  // zero all rows and exit
    float4* o4 = (float4*)outSlab;
    for (int i = tid; i < TOPK * ROWW / 4; i += 256) o4[i] = z4;
    return;
  }

  // ---- bitonic sort by (score desc, idx asc) — lax.top_k tie semantics ----
  int P = 1;
  while (P < M) P <<= 1;
  for (int i = M + tid; i < P; i += 256) {
    cscore[i] = -1e30f;
    cidx[i] = 0x7fffffff;
  }
  __syncthreads();
  for (int k = 2; k <= P; k <<= 1) {
    for (int j = k >> 1; j > 0; j >>= 1) {
      for (int i = tid; i < P; i += 256) {
        int ixj = i ^ j;
        if (ixj > i) {
          float si = cscore[i], sj = cscore[ixj];
          int ii = cidx[i], ij = cidx[ixj];
          bool agt = (si > sj) || (si == sj && ii < ij);
          bool up = ((i & k) == 0);
          if (up ? !agt : agt) {
            cscore[i] = sj; cscore[ixj] = si;
            cidx[i] = ij;  cidx[ixj] = ii;
          }
        }
      }
      __syncthreads();
    }
  }

  const int K = M < TOPK ? M : TOPK;

  // ---- decode candidate boxes, f32, reference op order ----
  const float* locB = loc + (size_t)b * NN * 4;
  for (int t = tid; t < K; t += 256) {
    int n = cidx[t];
    float l0 = locB[(size_t)n * 4 + 0], l1 = locB[(size_t)n * 4 + 1];
    float l2 = locB[(size_t)n * 4 + 2], l3 = locB[(size_t)n * 4 + 3];
    float d0 = dbox[(size_t)n * 4 + 0], d1 = dbox[(size_t)n * 4 + 1];
    float d2 = dbox[(size_t)n * 4 + 2], d3 = dbox[(size_t)n * 4 + 3];
    float cx = d0 + (l0 * 0.1f) * d2;
    float cy = d1 + (l1 * 0.1f) * d3;
    float w = d2 * (float)fexp((double)(l2 * 0.2f));
    float h = d3 * (float)fexp((double)(l3 * 0.2f));
    float x1 = cx - w * 0.5f;
    float y1 = cy - h * 0.5f;
    float x2 = x1 + w;
    float y2 = y1 + h;
    bx1[t] = x1; by1[t] = y1; bx2[t] = x2; by2[t] = y2;
    barea[t] = (x2 - x1) * (y2 - y1);
  }
  __syncthreads();

  // ---- parallel suppression matrix: wave wv owns 64-lane word wv ----
  {
    const int l = wv * 64 + lane;
    float lx1 = 0.f, ly1 = 0.f, lx2 = 0.f, ly2 = 0.f, lar = 0.f;
    const bool lvalid = l < K;
    if (lvalid) { lx1 = bx1[l]; ly1 = by1[l]; lx2 = bx2[l]; ly2 = by2[l]; lar = barea[l]; }
    const int wtop = wv * 64 + 63;
    for (int j = 0; j < K; ++j) {
      unsigned long long mres = 0;
      if (wtop > j) {  // wave-uniform: some l>j exists in this word
        float jx1 = bx1[j], jy1 = by1[j], jx2 = bx2[j], jy2 = by2[j], ja = barea[j];
        float xx1 = fmaxf(lx1, jx1);
        float yy1 = fmaxf(ly1, jy1);
        float xx2 = fminf(lx2, jx2);
        float yy2 = fminf(ly2, jy2);
        float iw = fmaxf(xx2 - xx1, 0.0f);
        float ih = fmaxf(yy2 - yy1, 0.0f);
        float inter = iw * ih;
        float uni = (lar - inter) + ja;         // area - inter + area[i]
        bool hit = lvalid & (l > j) & (inter / uni > 0.45f);
        mres = __ballot((int)hit);
      }
      if (lane == 0) supp[j * 4 + wv] = mres;
    }
  }
  __syncthreads();

  // ---- serial greedy: nk iterations only (ffs over alive bitset) ----
  if (tid == 0) {
    unsigned long long alive[4];
#pragma unroll
    for (int w = 0; w < 4; ++w) {
      int cnt = K - w * 64;
      alive[w] = cnt <= 0 ? 0ull : (cnt >= 64 ? ~0ull : ((1ull << cnt) - 1ull));
    }
    int nk = 0;
#pragma unroll
    for (int w = 0; w < 4; ++w) {
      while (alive[w]) {
        int bit = __ffsll(alive[w]) - 1;
        int j = w * 64 + bit;
        kept[nk++] = j;
        unsigned long long r0 = supp[j * 4 + 0];
        unsigned long long r1 = supp[j * 4 + 1];
        unsigned long long r2 = supp[j * 4 + 2];
        unsigned long long r3 = supp[j * 4 + 3];
        alive[w] &= ~(1ull << bit);
        alive[0] &= ~r0; alive[1] &= ~r1; alive[2] &= ~r2; alive[3] &= ~r3;
      }
    }
    sKept = nk;
  }
  __syncthreads();

  // ---- write kept rows, then zero only the tail rows ----
  const int nk = sKept;
  const float* poseB = pose + (size_t)b * NN * NPOSE;
  const float* lineB = line + (size_t)b * NN * NLINE;
  for (int t = tid; t < nk; t += 256) {
    int j = kept[t];
    int n = cidx[j];
    float* row = outSlab + (size_t)t * ROWW;
    row[0] = cscore[j];
    row[1] = bx1[j];
    row[2] = by1[j];
    row[3] = bx2[j];
    row[4] = by2[j];
    const float4* p4 = (const float4*)(poseB + (size_t)n * NPOSE);
#pragma unroll
    for (int q = 0; q < 8; ++q) {
      float4 pv = p4[q];
      row[5 + 4 * q + 0] = pv.x;
      row[5 + 4 * q + 1] = pv.y;
      row[5 + 4 * q + 2] = pv.z;
      row[5 + 4 * q + 3] = pv.w;
    }
    row[37] = lineB[(size_t)n * NLINE + 0];
    row[38] = lineB[(size_t)n * NLINE + 1];
    row[39] = lineB[(size_t)n * NLINE + 2];
  }
  {  // rows [nk, TOPK): 10 float4 per row
    const int zq = (TOPK - nk) * 10;
    float4* o4 = (float4*)(outSlab + (size_t)nk * ROWW);
    for (int q = tid; q < zq; q += 256) o4[q] = z4;
  }
}

// ---------------------------------------------------------------------------
extern "C" void kernel_launch(void* const* d_in, const int* in_sizes, int n_in,
                              void* d_out, int out_size, void* d_ws, size_t ws_size,
                              hipStream_t stream) {
  const float* loc  = (const float*)d_in[0];
  const float* conf = (const float*)d_in[1];
  const float* pose = (const float*)d_in[2];
  const float* line = (const float*)d_in[3];
  const float* dbox = (const float*)d_in[4];
  float* out = (float*)d_out;

  const size_t scoreBytes = (size_t)BB * CC * NN * sizeof(float);   // ~23.5 MB
  const size_t auxBytes   = (size_t)BB * NN * sizeof(float2);       // ~2.2 MB

  int mode;
  float* scores = nullptr;
  float2* aux = nullptr;
  if (ws_size >= scoreBytes) {
    mode = 2; scores = (float*)d_ws;
  } else if (ws_size >= auxBytes) {
    mode = 1; aux = (float2*)d_ws;
  } else {
    mode = 0;
  }

  const int total = BB * NN;
  if (mode == 2) {
    score_kernel<<<(total + 255) / 256, 256, 0, stream>>>(conf, scores);
  } else if (mode == 1) {
    aux_kernel<<<(total + 255) / 256, 256, 0, stream>>>(conf, aux);
  }
  nms_kernel<<<BB * CC, 256, 0, stream>>>(loc, conf, pose, line, dbox,
                                          scores, aux, mode, out);
}